// Round 5
// baseline (1546.853 us; speedup 1.0000x reference)
//
#include <hip/hip_runtime.h>
#include <stdint.h>

#define N_NODES 50000
#define N_EDGES 400000
#define DDIM 256
#define PAD 260  // LDS row stride (floats): 16B-aligned float4s + bank-spread

// ---------------------------------------------------------------------------
// JAX threefry2x32, key = (0, 42).  Partitionable scheme (JAX >= 0.4.36
// default): element with flat index j uses counter (hi,lo) = (0, j) via
// iota_2x32_shape; 32-bit draw = bits1 ^ bits2 (out0 XOR out1).
// ---------------------------------------------------------------------------
__device__ __forceinline__ uint32_t rotl32(uint32_t x, uint32_t r) {
  return (x << r) | (x >> (32u - r));
}

__device__ __forceinline__ void threefry2x32_0_42(uint32_t x0, uint32_t x1,
                                                  uint32_t& o0, uint32_t& o1) {
  const uint32_t k0 = 0u, k1 = 42u;
  const uint32_t k2 = k0 ^ k1 ^ 0x1BD11BDAu;
  x0 += k0;
  x1 += k1;
#define TF_ROUND(r)          \
  {                          \
    x0 += x1;                \
    x1 = rotl32(x1, r);      \
    x1 ^= x0;                \
  }
  TF_ROUND(13) TF_ROUND(15) TF_ROUND(26) TF_ROUND(6)
  x0 += k1; x1 += k2 + 1u;
  TF_ROUND(17) TF_ROUND(29) TF_ROUND(16) TF_ROUND(24)
  x0 += k2; x1 += k0 + 2u;
  TF_ROUND(13) TF_ROUND(15) TF_ROUND(26) TF_ROUND(6)
  x0 += k0; x1 += k1 + 3u;
  TF_ROUND(17) TF_ROUND(29) TF_ROUND(16) TF_ROUND(24)
  x0 += k1; x1 += k2 + 4u;
  TF_ROUND(13) TF_ROUND(15) TF_ROUND(26) TF_ROUND(6)
  x0 += k2; x1 += k0 + 5u;
#undef TF_ROUND
  o0 = x0;
  o1 = x1;
}

// ---------------------------------------------------------------------------
// 1) degrees from edge list
// ---------------------------------------------------------------------------
__global__ __launch_bounds__(256) void degree_kernel(
    const int* __restrict__ src, const int* __restrict__ dst,
    float* __restrict__ deg_out, float* __restrict__ deg_in) {
  const int e = blockIdx.x * 256 + threadIdx.x;
  if (e < N_EDGES) {
    unsafeAtomicAdd(&deg_out[src[e]], 1.0f);
    unsafeAtomicAdd(&deg_in[dst[e]], 1.0f);
  }
}

// ---------------------------------------------------------------------------
// 2) agg[dst] += feat[src] * rsqrt(max(deg_out[src],1))  -> into d_out (fp32)
//    one wave per edge
// ---------------------------------------------------------------------------
__global__ __launch_bounds__(256) void agg_kernel(
    const float* __restrict__ feat, const float* __restrict__ deg_out,
    const int* __restrict__ src, const int* __restrict__ dst,
    float* __restrict__ agg) {
  const int e = blockIdx.x * 4 + (threadIdx.x >> 6);
  const int lane = threadIdx.x & 63;
  if (e >= N_EDGES) return;
  const int s = src[e];
  const int t = dst[e];
  const float sc = rsqrtf(fmaxf(deg_out[s], 1.0f));
  const float4 v = *(const float4*)(feat + (size_t)s * DDIM + lane * 4);
  float* agr = agg + (size_t)t * DDIM + lane * 4;
  unsafeAtomicAdd(agr + 0, v.x * sc);
  unsafeAtomicAdd(agr + 1, v.y * sc);
  unsafeAtomicAdd(agr + 2, v.z * sc);
  unsafeAtomicAdd(agr + 3, v.w * sc);
}

// ---------------------------------------------------------------------------
// 3) out = dropout(relu((agg @ W) * rsqrt(max(deg_in,1)) + b))  IN-PLACE over
//    the agg stored in d_out.  One block owns a full 64-row x 256-col slab:
//    block reads ONLY its own rows (staged to LDS before any write), so
//    in-place is hazard-free.  256 threads: (ty,tx) computes rows 4ty..4ty+3
//    x cols {tx+16j}.
// ---------------------------------------------------------------------------
__global__ __launch_bounds__(256) void gemm_kernel(
    const float* __restrict__ W, const float* __restrict__ bias,
    const float* __restrict__ deg_in, float* __restrict__ out) {
  __shared__ float As[64 * PAD];  // [row][k]
  __shared__ float Ws[8 * PAD];   // [k][n]
  const int tid = threadIdx.x;
  const int r0 = blockIdx.x * 64;

  // stage A: rows r0..r0+63, k 0..255 (contiguous 16384 floats in d_out)
  {
    const float* base = out + (size_t)r0 * DDIM;
#pragma unroll
    for (int t = 0; t < 16; ++t) {
      const int idx = tid + 256 * t;  // float4 index within slab
      const int row = idx >> 6;       // 0..63 (wave-uniform)
      const int k4 = (idx & 63) << 2;
      float4 v = make_float4(0.f, 0.f, 0.f, 0.f);
      if (r0 + row < N_NODES) v = *(const float4*)(base + (size_t)idx * 4);
      *(float4*)&As[row * PAD + k4] = v;  // PAD*4 % 16 == 0 -> aligned
    }
  }

  const int tx = tid & 15;
  const int ty = tid >> 4;
  float acc[4][16] = {};

  for (int kk = 0; kk < 256; kk += 8) {
    __syncthreads();  // A staged (iter 0) / prev-iter Ws readers done
    {
      const float* wb = W + (size_t)kk * DDIM;
#pragma unroll
      for (int t = 0; t < 2; ++t) {
        const int idx = tid + 256 * t;
        const int kr = idx >> 6;  // 0..7
        const int c4 = (idx & 63) << 2;
        *(float4*)&Ws[kr * PAD + c4] = *(const float4*)(wb + (size_t)idx * 4);
      }
    }
    __syncthreads();
#pragma unroll
    for (int k = 0; k < 8; ++k) {
      float a[4];
#pragma unroll
      for (int i = 0; i < 4; ++i) a[i] = As[(ty * 4 + i) * PAD + kk + k];
#pragma unroll
      for (int j = 0; j < 16; ++j) {
        const float w = Ws[k * PAD + tx + 16 * j];
#pragma unroll
        for (int i = 0; i < 4; ++i) acc[i][j] += a[i] * w;
      }
    }
  }

  // epilogue: writes only this block's rows; all A reads already in LDS/acc
#pragma unroll
  for (int i = 0; i < 4; ++i) {
    const int row = r0 + ty * 4 + i;
    if (row >= N_NODES) break;
    const float s = rsqrtf(fmaxf(deg_in[row], 1.0f));
#pragma unroll
    for (int j = 0; j < 16; ++j) {
      const int col = tx + 16 * j;
      float v = acc[i][j] * s + bias[col];
      v = fmaxf(v, 0.0f);
      // partitionable threefry draw: ctr=(0,flat), bits = out0 ^ out1
      const uint32_t flat = (uint32_t)row * 256u + (uint32_t)col;
      uint32_t o0, o1;
      threefry2x32_0_42(0u, flat, o0, o1);
      const uint32_t bits = o0 ^ o1;
      const float u = __uint_as_float((bits >> 9) | 0x3F800000u) - 1.0f;
      out[(size_t)row * DDIM + col] = (u < 0.9f) ? (v / 0.9f) : 0.0f;
    }
  }
}

// ---------------------------------------------------------------------------
// ws layout (floats): deg_out [0,50000), deg_in [50000,100000).  400 KB total.
// agg lives in d_out itself (51.2 MB, zeroed each launch).
// ---------------------------------------------------------------------------
extern "C" void kernel_launch(void* const* d_in, const int* in_sizes, int n_in,
                              void* d_out, int out_size, void* d_ws, size_t ws_size,
                              hipStream_t stream) {
  const float* feat = (const float*)d_in[0];
  const float* W = (const float*)d_in[1];
  const float* bias = (const float*)d_in[2];
  const int* src = (const int*)d_in[3];
  const int* dst = (const int*)d_in[4];
  float* out = (float*)d_out;

  float* deg_out = (float*)d_ws;
  float* deg_in = deg_out + N_NODES;

  hipMemsetAsync(d_ws, 0, 2u * N_NODES * sizeof(float), stream);
  hipMemsetAsync(d_out, 0, (size_t)N_NODES * DDIM * sizeof(float), stream);

  degree_kernel<<<(N_EDGES + 255) / 256, 256, 0, stream>>>(src, dst, deg_out, deg_in);
  agg_kernel<<<N_EDGES / 4, 256, 0, stream>>>(feat, deg_out, src, dst, out);
  gemm_kernel<<<(N_NODES + 63) / 64, 256, 0, stream>>>(W, bias, deg_in, out);
}

// Round 6
// 381.083 us; speedup vs baseline: 4.0591x; 4.0591x over previous
//
#include <hip/hip_runtime.h>
#include <stdint.h>

#define N_NODES 50000
#define N_EDGES 400000
#define DDIM 256
#define PAD 260  // LDS row stride (floats): 16B-aligned float4s + bank-spread

// ---------------------------------------------------------------------------
// JAX threefry2x32, key = (0, 42).  Partitionable scheme (verified round 5):
// element with flat index j uses counter (0, j); draw = out0 ^ out1.
// ---------------------------------------------------------------------------
__device__ __forceinline__ uint32_t rotl32(uint32_t x, uint32_t r) {
  return (x << r) | (x >> (32u - r));
}

__device__ __forceinline__ uint32_t threefry_draw_0_42(uint32_t x0, uint32_t x1) {
  const uint32_t k0 = 0u, k1 = 42u;
  const uint32_t k2 = k0 ^ k1 ^ 0x1BD11BDAu;
  x0 += k0;
  x1 += k1;
#define TF_ROUND(r)          \
  {                          \
    x0 += x1;                \
    x1 = rotl32(x1, r);      \
    x1 ^= x0;                \
  }
  TF_ROUND(13) TF_ROUND(15) TF_ROUND(26) TF_ROUND(6)
  x0 += k1; x1 += k2 + 1u;
  TF_ROUND(17) TF_ROUND(29) TF_ROUND(16) TF_ROUND(24)
  x0 += k2; x1 += k0 + 2u;
  TF_ROUND(13) TF_ROUND(15) TF_ROUND(26) TF_ROUND(6)
  x0 += k0; x1 += k1 + 3u;
  TF_ROUND(17) TF_ROUND(29) TF_ROUND(16) TF_ROUND(24)
  x0 += k1; x1 += k2 + 4u;
  TF_ROUND(13) TF_ROUND(15) TF_ROUND(26) TF_ROUND(6)
  x0 += k2; x1 += k0 + 5u;
#undef TF_ROUND
  return x0 ^ x1;
}

// ---------------------------------------------------------------------------
// 1) integer degrees from edge list
// ---------------------------------------------------------------------------
__global__ __launch_bounds__(256) void degree_kernel(
    const int* __restrict__ src, const int* __restrict__ dst,
    int* __restrict__ deg_out, int* __restrict__ deg_in) {
  const int e = blockIdx.x * 256 + threadIdx.x;
  if (e < N_EDGES) {
    atomicAdd(&deg_out[src[e]], 1);
    atomicAdd(&deg_in[dst[e]], 1);
  }
}

// ---------------------------------------------------------------------------
// 2) exclusive prefix scan of deg_in -> row_ptr[50001], cursor copy.
//    Single block, 1024 threads, 49 elems/thread + Hillis-Steele on totals.
// ---------------------------------------------------------------------------
#define CHUNK 49  // 1024*49 = 50176 >= 50000
__global__ __launch_bounds__(1024) void scan_kernel(
    const int* __restrict__ deg_in, int* __restrict__ row_ptr,
    int* __restrict__ cursor) {
  __shared__ int sums[1024];
  const int tid = threadIdx.x;
  const int start = tid * CHUNK;
  const int end = min(start + CHUNK, N_NODES);
  int s = 0;
  for (int i = start; i < end; ++i) s += deg_in[i];
  sums[tid] = s;
  __syncthreads();
  for (int off = 1; off < 1024; off <<= 1) {
    const int v = sums[tid];
    const int add = (tid >= off) ? sums[tid - off] : 0;
    __syncthreads();
    sums[tid] = v + add;
    __syncthreads();
  }
  int run = (tid == 0) ? 0 : sums[tid - 1];
  for (int i = start; i < end; ++i) {
    row_ptr[i] = run;
    cursor[i] = run;
    run += deg_in[i];
  }
  if (tid == 1023) row_ptr[N_NODES] = sums[1023];
}

// ---------------------------------------------------------------------------
// 3) counting-sort edges by dst: esrc[row_ptr[dst] ..] = src
// ---------------------------------------------------------------------------
__global__ __launch_bounds__(256) void fill_kernel(
    const int* __restrict__ src, const int* __restrict__ dst,
    int* __restrict__ cursor, int* __restrict__ esrc) {
  const int e = blockIdx.x * 256 + threadIdx.x;
  if (e < N_EDGES) {
    const int pos = atomicAdd(&cursor[dst[e]], 1);
    esrc[pos] = src[e];
  }
}

// ---------------------------------------------------------------------------
// 4) pull-mode aggregate: one wave per dst node, no atomics.
//    agg[n] = sum_{e in CSR[n]} feat[esrc[e]] * rsqrt(max(deg_out,1))
//    -> written once into d_out (fp32)
// ---------------------------------------------------------------------------
__global__ __launch_bounds__(256) void gather_kernel(
    const float* __restrict__ feat, const int* __restrict__ deg_out,
    const int* __restrict__ row_ptr, const int* __restrict__ esrc,
    float* __restrict__ agg) {
  const int n = blockIdx.x * 4 + (threadIdx.x >> 6);
  const int lane = threadIdx.x & 63;
  if (n >= N_NODES) return;
  const int beg = row_ptr[n];
  const int fin = row_ptr[n + 1];
  float4 acc = make_float4(0.f, 0.f, 0.f, 0.f);
  for (int j = beg; j < fin; ++j) {
    const int s = esrc[j];
    const float sc = rsqrtf(fmaxf((float)deg_out[s], 1.0f));
    const float4 v = *(const float4*)(feat + (size_t)s * DDIM + lane * 4);
    acc.x += v.x * sc;
    acc.y += v.y * sc;
    acc.z += v.z * sc;
    acc.w += v.w * sc;
  }
  *(float4*)(agg + (size_t)n * DDIM + lane * 4) = acc;
}

// ---------------------------------------------------------------------------
// 5) out = dropout(relu((agg @ W) * rsqrt(max(deg_in,1)) + b))  IN-PLACE over
//    the agg stored in d_out (block stages its own 64 rows to LDS first).
// ---------------------------------------------------------------------------
__global__ __launch_bounds__(256) void gemm_kernel(
    const float* __restrict__ W, const float* __restrict__ bias,
    const int* __restrict__ deg_in, float* __restrict__ out) {
  __shared__ float As[64 * PAD];  // [row][k]
  __shared__ float Ws[8 * PAD];   // [k][n]
  const int tid = threadIdx.x;
  const int r0 = blockIdx.x * 64;

  {
    const float* base = out + (size_t)r0 * DDIM;
#pragma unroll
    for (int t = 0; t < 16; ++t) {
      const int idx = tid + 256 * t;  // float4 index within slab
      const int row = idx >> 6;
      const int k4 = (idx & 63) << 2;
      float4 v = make_float4(0.f, 0.f, 0.f, 0.f);
      if (r0 + row < N_NODES) v = *(const float4*)(base + (size_t)idx * 4);
      *(float4*)&As[row * PAD + k4] = v;
    }
  }

  const int tx = tid & 15;
  const int ty = tid >> 4;
  float acc[4][16] = {};

  for (int kk = 0; kk < 256; kk += 8) {
    __syncthreads();
    {
      const float* wb = W + (size_t)kk * DDIM;
#pragma unroll
      for (int t = 0; t < 2; ++t) {
        const int idx = tid + 256 * t;
        const int kr = idx >> 6;
        const int c4 = (idx & 63) << 2;
        *(float4*)&Ws[kr * PAD + c4] = *(const float4*)(wb + (size_t)idx * 4);
      }
    }
    __syncthreads();
#pragma unroll
    for (int k = 0; k < 8; ++k) {
      float a[4];
#pragma unroll
      for (int i = 0; i < 4; ++i) a[i] = As[(ty * 4 + i) * PAD + kk + k];
#pragma unroll
      for (int j = 0; j < 16; ++j) {
        const float w = Ws[k * PAD + tx + 16 * j];
#pragma unroll
        for (int i = 0; i < 4; ++i) acc[i][j] += a[i] * w;
      }
    }
  }

#pragma unroll
  for (int i = 0; i < 4; ++i) {
    const int row = r0 + ty * 4 + i;
    if (row >= N_NODES) break;
    const float s = rsqrtf(fmaxf((float)deg_in[row], 1.0f));
#pragma unroll
    for (int j = 0; j < 16; ++j) {
      const int col = tx + 16 * j;
      float v = acc[i][j] * s + bias[col];
      v = fmaxf(v, 0.0f);
      const uint32_t flat = (uint32_t)row * 256u + (uint32_t)col;
      const uint32_t bits = threefry_draw_0_42(0u, flat);
      const float u = __uint_as_float((bits >> 9) | 0x3F800000u) - 1.0f;
      out[(size_t)row * DDIM + col] = (u < 0.9f) ? (v / 0.9f) : 0.0f;
    }
  }
}

// ---------------------------------------------------------------------------
// ws layout (ints):
//   [0, 50000)        deg_out
//   [50000, 100000)   deg_in
//   [100000, 150001)  row_ptr
//   [150008, 200008)  cursor
//   [200008, 600008)  esrc (edge srcs sorted by dst)
// total 2.4 MB
// ---------------------------------------------------------------------------
extern "C" void kernel_launch(void* const* d_in, const int* in_sizes, int n_in,
                              void* d_out, int out_size, void* d_ws, size_t ws_size,
                              hipStream_t stream) {
  const float* feat = (const float*)d_in[0];
  const float* W = (const float*)d_in[1];
  const float* bias = (const float*)d_in[2];
  const int* src = (const int*)d_in[3];
  const int* dst = (const int*)d_in[4];
  float* out = (float*)d_out;

  int* iws = (int*)d_ws;
  int* deg_out = iws;
  int* deg_in = iws + 50000;
  int* row_ptr = iws + 100000;
  int* cursor = iws + 150008;
  int* esrc = iws + 200008;

  hipMemsetAsync(d_ws, 0, 100000 * sizeof(int), stream);  // degrees only

  degree_kernel<<<(N_EDGES + 255) / 256, 256, 0, stream>>>(src, dst, deg_out, deg_in);
  scan_kernel<<<1, 1024, 0, stream>>>(deg_in, row_ptr, cursor);
  fill_kernel<<<(N_EDGES + 255) / 256, 256, 0, stream>>>(src, dst, cursor, esrc);
  gather_kernel<<<(N_NODES + 3) / 4, 256, 0, stream>>>(feat, deg_out, row_ptr, esrc, out);
  gemm_kernel<<<(N_NODES + 63) / 64, 256, 0, stream>>>(W, bias, deg_in, out);
}

// Round 7
// 289.709 us; speedup vs baseline: 5.3393x; 1.3154x over previous
//
#include <hip/hip_runtime.h>
#include <stdint.h>

#define N_NODES 50000
#define N_EDGES 400000
#define DDIM 256

typedef __attribute__((ext_vector_type(8))) short bf16x8;
typedef __attribute__((ext_vector_type(4))) float f32x4;

// ---------------------------------------------------------------------------
// JAX threefry2x32, key = (0, 42).  Partitionable scheme (verified round 5):
// element with flat index j uses counter (0, j); draw = out0 ^ out1.
// ---------------------------------------------------------------------------
__device__ __forceinline__ uint32_t rotl32(uint32_t x, uint32_t r) {
  return (x << r) | (x >> (32u - r));
}

__device__ __forceinline__ uint32_t threefry_draw_0_42(uint32_t x0, uint32_t x1) {
  const uint32_t k0 = 0u, k1 = 42u;
  const uint32_t k2 = k0 ^ k1 ^ 0x1BD11BDAu;
  x0 += k0;
  x1 += k1;
#define TF_ROUND(r)          \
  {                          \
    x0 += x1;                \
    x1 = rotl32(x1, r);      \
    x1 ^= x0;                \
  }
  TF_ROUND(13) TF_ROUND(15) TF_ROUND(26) TF_ROUND(6)
  x0 += k1; x1 += k2 + 1u;
  TF_ROUND(17) TF_ROUND(29) TF_ROUND(16) TF_ROUND(24)
  x0 += k2; x1 += k0 + 2u;
  TF_ROUND(13) TF_ROUND(15) TF_ROUND(26) TF_ROUND(6)
  x0 += k0; x1 += k1 + 3u;
  TF_ROUND(17) TF_ROUND(29) TF_ROUND(16) TF_ROUND(24)
  x0 += k1; x1 += k2 + 4u;
  TF_ROUND(13) TF_ROUND(15) TF_ROUND(26) TF_ROUND(6)
  x0 += k2; x1 += k0 + 5u;
#undef TF_ROUND
  return x0 ^ x1;
}

__device__ __forceinline__ uint16_t bf16_rne(float x) {
  uint32_t u = __float_as_uint(x);
  u += 0x7FFFu + ((u >> 16) & 1u);
  return (uint16_t)(u >> 16);
}

// ---------------------------------------------------------------------------
// 0) W fp32 [k][n] -> Wt bf16 [n][k]  (128 KB, L2-resident for gemm)
// ---------------------------------------------------------------------------
__global__ __launch_bounds__(256) void wconv_kernel(
    const float* __restrict__ W, uint16_t* __restrict__ Wt) {
  const int t = blockIdx.x * 256 + threadIdx.x;  // 16384 threads
  const int n = t >> 6;
  const int k4 = (t & 63) << 2;
  ushort4 p;
  p.x = bf16_rne(W[(size_t)(k4 + 0) * DDIM + n]);
  p.y = bf16_rne(W[(size_t)(k4 + 1) * DDIM + n]);
  p.z = bf16_rne(W[(size_t)(k4 + 2) * DDIM + n]);
  p.w = bf16_rne(W[(size_t)(k4 + 3) * DDIM + n]);
  *(ushort4*)(Wt + (size_t)n * DDIM + k4) = p;
}

// ---------------------------------------------------------------------------
// 1) integer degrees from edge list
// ---------------------------------------------------------------------------
__global__ __launch_bounds__(256) void degree_kernel(
    const int* __restrict__ src, const int* __restrict__ dst,
    int* __restrict__ deg_out, int* __restrict__ deg_in) {
  const int e = blockIdx.x * 256 + threadIdx.x;
  if (e < N_EDGES) {
    atomicAdd(&deg_out[src[e]], 1);
    atomicAdd(&deg_in[dst[e]], 1);
  }
}

// ---------------------------------------------------------------------------
// 2) exclusive prefix scan of deg_in -> row_ptr[50001], cursor copy.
// ---------------------------------------------------------------------------
#define CHUNK 49  // 1024*49 = 50176 >= 50000
__global__ __launch_bounds__(1024) void scan_kernel(
    const int* __restrict__ deg_in, int* __restrict__ row_ptr,
    int* __restrict__ cursor) {
  __shared__ int sums[1024];
  const int tid = threadIdx.x;
  const int start = tid * CHUNK;
  const int end = min(start + CHUNK, N_NODES);
  int s = 0;
  for (int i = start; i < end; ++i) s += deg_in[i];
  sums[tid] = s;
  __syncthreads();
  for (int off = 1; off < 1024; off <<= 1) {
    const int v = sums[tid];
    const int add = (tid >= off) ? sums[tid - off] : 0;
    __syncthreads();
    sums[tid] = v + add;
    __syncthreads();
  }
  int run = (tid == 0) ? 0 : sums[tid - 1];
  for (int i = start; i < end; ++i) {
    row_ptr[i] = run;
    cursor[i] = run;
    run += deg_in[i];
  }
  if (tid == 1023) row_ptr[N_NODES] = sums[1023];
}

// ---------------------------------------------------------------------------
// 3) counting-sort edges by dst
// ---------------------------------------------------------------------------
__global__ __launch_bounds__(256) void fill_kernel(
    const int* __restrict__ src, const int* __restrict__ dst,
    int* __restrict__ cursor, int* __restrict__ esrc) {
  const int e = blockIdx.x * 256 + threadIdx.x;
  if (e < N_EDGES) {
    const int pos = atomicAdd(&cursor[dst[e]], 1);
    esrc[pos] = src[e];
  }
}

// ---------------------------------------------------------------------------
// 4) pull-mode aggregate, fp32 accumulate -> bf16 store into ws
// ---------------------------------------------------------------------------
__global__ __launch_bounds__(256) void gather_kernel(
    const float* __restrict__ feat, const int* __restrict__ deg_out,
    const int* __restrict__ row_ptr, const int* __restrict__ esrc,
    uint16_t* __restrict__ agg) {
  const int n = blockIdx.x * 4 + (threadIdx.x >> 6);
  const int lane = threadIdx.x & 63;
  if (n >= N_NODES) return;
  const int beg = row_ptr[n];
  const int fin = row_ptr[n + 1];
  float4 acc = make_float4(0.f, 0.f, 0.f, 0.f);
  for (int j = beg; j < fin; ++j) {
    const int s = esrc[j];
    const float sc = rsqrtf(fmaxf((float)deg_out[s], 1.0f));
    const float4 v = *(const float4*)(feat + (size_t)s * DDIM + lane * 4);
    acc.x += v.x * sc;
    acc.y += v.y * sc;
    acc.z += v.z * sc;
    acc.w += v.w * sc;
  }
  ushort4 p;
  p.x = bf16_rne(acc.x);
  p.y = bf16_rne(acc.y);
  p.z = bf16_rne(acc.z);
  p.w = bf16_rne(acc.w);
  *(ushort4*)(agg + (size_t)n * DDIM + lane * 4) = p;
}

// ---------------------------------------------------------------------------
// 5) out = dropout(relu((agg @ W) * rsqrt(max(deg_in,1)) + b))
//    MFMA bf16 16x16x32.  Block = 64 rows x 256 cols, 4 waves (wave: 64x64).
//    As[64][280] staged once; Bs[256][40] streamed per BK=32 from Wt.
//    Pads keep b128 16B-aligned with <=2-way bank aliasing.
// ---------------------------------------------------------------------------
#define APAD 280  // shorts per As row (560 B, 16B-aligned, 2-way banks)
#define BPAD 40   // shorts per Bs row (80 B, 16B-aligned, 2-way banks)
__global__ __launch_bounds__(256) void gemm_mfma_kernel(
    const uint16_t* __restrict__ agg, const uint16_t* __restrict__ Wt,
    const float* __restrict__ bias, const int* __restrict__ deg_in,
    float* __restrict__ out) {
  __shared__ short As[64 * APAD];
  __shared__ short Bs[256 * BPAD];
  __shared__ float sdeg[64];
  __shared__ float sbias[256];

  const int tid = threadIdx.x;
  const int r0 = blockIdx.x * 64;
  const int lane = tid & 63;
  const int seg = lane >> 4;  // k-segment 0..3
  const int l15 = lane & 15;
  const int wc = tid >> 6;  // wave -> col panel (64 cols each)

  sbias[tid] = bias[tid];
  if (tid < 64) {
    const int r = r0 + tid;
    sdeg[tid] = (r < N_NODES) ? rsqrtf(fmaxf((float)deg_in[r], 1.0f)) : 0.0f;
  }

  // stage A panel: 64 rows x 256 k bf16 (2048 x 16B chunks, coalesced)
  {
    const uint16_t* ap = agg + (size_t)r0 * DDIM;
#pragma unroll
    for (int it = 0; it < 8; ++it) {
      const int c = tid + 256 * it;
      const int row = c >> 5;        // 32 chunks per row
      const int k8 = (c & 31) << 3;  // 0,8,...,248
      int4 v = make_int4(0, 0, 0, 0);
      if (r0 + row < N_NODES) v = *(const int4*)(ap + (size_t)row * DDIM + k8);
      *(int4*)&As[row * APAD + k8] = v;
    }
  }

  f32x4 acc[4][4] = {};

  for (int kk = 0; kk < 256; kk += 32) {
    __syncthreads();  // A staged (first iter) / prev-iter Bs readers done
    // stage Bs: 256 n x 32 k bf16 from Wt (L2-resident)
#pragma unroll
    for (int it = 0; it < 4; ++it) {
      const int c = tid + 256 * it;  // 0..1023
      const int n = c >> 2;
      const int k8 = (c & 3) << 3;
      *(int4*)&Bs[n * BPAD + k8] = *(const int4*)(Wt + (size_t)n * DDIM + kk + k8);
    }
    __syncthreads();

    bf16x8 a[4], b[4];
#pragma unroll
    for (int m = 0; m < 4; ++m)
      a[m] = *(const bf16x8*)&As[(m * 16 + l15) * APAD + kk + seg * 8];
#pragma unroll
    for (int n = 0; n < 4; ++n)
      b[n] = *(const bf16x8*)&Bs[(wc * 64 + n * 16 + l15) * BPAD + seg * 8];
#pragma unroll
    for (int m = 0; m < 4; ++m)
#pragma unroll
      for (int n = 0; n < 4; ++n)
        acc[m][n] = __builtin_amdgcn_mfma_f32_16x16x32_bf16(a[m], b[n], acc[m][n], 0, 0, 0);
  }

  // epilogue: C/D layout col = lane&15, row = seg*4 + reg
#pragma unroll
  for (int m = 0; m < 4; ++m) {
#pragma unroll
    for (int r = 0; r < 4; ++r) {
      const int lrow = m * 16 + seg * 4 + r;
      const int row = r0 + lrow;
      if (row >= N_NODES) continue;
      const float s = sdeg[lrow];
#pragma unroll
      for (int n = 0; n < 4; ++n) {
        const int col = wc * 64 + n * 16 + l15;
        float v = acc[m][n][r] * s + sbias[col];
        v = fmaxf(v, 0.0f);
        const uint32_t flat = (uint32_t)row * 256u + (uint32_t)col;
        const uint32_t bits = threefry_draw_0_42(0u, flat);
        const float u = __uint_as_float((bits >> 9) | 0x3F800000u) - 1.0f;
        out[(size_t)row * DDIM + col] = (u < 0.9f) ? (v / 0.9f) : 0.0f;
      }
    }
  }
}

// ---------------------------------------------------------------------------
// ws layout:
//   ints:   deg_out [0,50000) | deg_in [50000,100000) | row_ptr [100000,150001)
//           cursor [150008,200008) | esrc [200008,600008)
//   bytes:  Wt bf16  @ 2400064  (131072 B)
//           agg bf16 @ 2531136  (25.6 MB)   total ~28.1 MB
// ---------------------------------------------------------------------------
extern "C" void kernel_launch(void* const* d_in, const int* in_sizes, int n_in,
                              void* d_out, int out_size, void* d_ws, size_t ws_size,
                              hipStream_t stream) {
  const float* feat = (const float*)d_in[0];
  const float* W = (const float*)d_in[1];
  const float* bias = (const float*)d_in[2];
  const int* src = (const int*)d_in[3];
  const int* dst = (const int*)d_in[4];
  float* out = (float*)d_out;

  int* iws = (int*)d_ws;
  int* deg_out = iws;
  int* deg_in = iws + 50000;
  int* row_ptr = iws + 100000;
  int* cursor = iws + 150008;
  int* esrc = iws + 200008;
  uint16_t* Wt = (uint16_t*)((char*)d_ws + 2400064);
  uint16_t* agg = (uint16_t*)((char*)d_ws + 2531136);

  hipMemsetAsync(d_ws, 0, 100000 * sizeof(int), stream);  // degrees only

  wconv_kernel<<<64, 256, 0, stream>>>(W, Wt);
  degree_kernel<<<(N_EDGES + 255) / 256, 256, 0, stream>>>(src, dst, deg_out, deg_in);
  scan_kernel<<<1, 1024, 0, stream>>>(deg_in, row_ptr, cursor);
  fill_kernel<<<(N_EDGES + 255) / 256, 256, 0, stream>>>(src, dst, cursor, esrc);
  gather_kernel<<<(N_NODES + 3) / 4, 256, 0, stream>>>(feat, deg_out, row_ptr, esrc, agg);
  gemm_mfma_kernel<<<(N_NODES + 63) / 64, 256, 0, stream>>>(agg, Wt, bias, deg_in, out);
}

// Round 8
// 190.370 us; speedup vs baseline: 8.1255x; 1.5218x over previous
//
#include <hip/hip_runtime.h>
#include <stdint.h>

#define N_NODES 50000
#define N_EDGES 400000
#define DDIM 256
#define SCAN_BLOCKS 196  // 196*256 = 50176 >= 50000

typedef __attribute__((ext_vector_type(8))) short bf16x8;
typedef __attribute__((ext_vector_type(4))) float f32x4;

// ---------------------------------------------------------------------------
// JAX threefry2x32, key = (0, 42).  Partitionable scheme (verified round 5):
// element with flat index j uses counter (0, j); draw = out0 ^ out1.
// ---------------------------------------------------------------------------
__device__ __forceinline__ uint32_t rotl32(uint32_t x, uint32_t r) {
  return (x << r) | (x >> (32u - r));
}

__device__ __forceinline__ uint32_t threefry_draw_0_42(uint32_t x0, uint32_t x1) {
  const uint32_t k0 = 0u, k1 = 42u;
  const uint32_t k2 = k0 ^ k1 ^ 0x1BD11BDAu;
  x0 += k0;
  x1 += k1;
#define TF_ROUND(r)          \
  {                          \
    x0 += x1;                \
    x1 = rotl32(x1, r);      \
    x1 ^= x0;                \
  }
  TF_ROUND(13) TF_ROUND(15) TF_ROUND(26) TF_ROUND(6)
  x0 += k1; x1 += k2 + 1u;
  TF_ROUND(17) TF_ROUND(29) TF_ROUND(16) TF_ROUND(24)
  x0 += k2; x1 += k0 + 2u;
  TF_ROUND(13) TF_ROUND(15) TF_ROUND(26) TF_ROUND(6)
  x0 += k0; x1 += k1 + 3u;
  TF_ROUND(17) TF_ROUND(29) TF_ROUND(16) TF_ROUND(24)
  x0 += k1; x1 += k2 + 4u;
  TF_ROUND(13) TF_ROUND(15) TF_ROUND(26) TF_ROUND(6)
  x0 += k2; x1 += k0 + 5u;
#undef TF_ROUND
  return x0 ^ x1;
}

__device__ __forceinline__ uint16_t bf16_rne(float x) {
  uint32_t u = __float_as_uint(x);
  u += 0x7FFFu + ((u >> 16) & 1u);
  return (uint16_t)(u >> 16);
}

__device__ __forceinline__ float bf16_to_f32(uint16_t x) {
  return __uint_as_float(((uint32_t)x) << 16);
}

// ---------------------------------------------------------------------------
// 0a) W fp32 [k][n] -> Wt bf16 [n][k]  (128 KB, L2-resident for gemm)
// ---------------------------------------------------------------------------
__global__ __launch_bounds__(256) void wconv_kernel(
    const float* __restrict__ W, uint16_t* __restrict__ Wt) {
  const int t = blockIdx.x * 256 + threadIdx.x;  // 16384 threads
  const int n = t >> 6;
  const int k4 = (t & 63) << 2;
  ushort4 p;
  p.x = bf16_rne(W[(size_t)(k4 + 0) * DDIM + n]);
  p.y = bf16_rne(W[(size_t)(k4 + 1) * DDIM + n]);
  p.z = bf16_rne(W[(size_t)(k4 + 2) * DDIM + n]);
  p.w = bf16_rne(W[(size_t)(k4 + 3) * DDIM + n]);
  *(ushort4*)(Wt + (size_t)n * DDIM + k4) = p;
}

// ---------------------------------------------------------------------------
// 0b) feat fp32 -> bf16 (into d_out scratch; halves gather read traffic)
// ---------------------------------------------------------------------------
__global__ __launch_bounds__(256) void fconv_kernel(
    const float* __restrict__ feat, uint16_t* __restrict__ featb) {
  const size_t base = ((size_t)blockIdx.x * 256 + threadIdx.x) * 8;
  const float4 a = *(const float4*)(feat + base);
  const float4 b = *(const float4*)(feat + base + 4);
  ushort4 lo, hi;
  lo.x = bf16_rne(a.x); lo.y = bf16_rne(a.y); lo.z = bf16_rne(a.z); lo.w = bf16_rne(a.w);
  hi.x = bf16_rne(b.x); hi.y = bf16_rne(b.y); hi.z = bf16_rne(b.z); hi.w = bf16_rne(b.w);
  *(ushort4*)(featb + base) = lo;
  *(ushort4*)(featb + base + 4) = hi;
}

// ---------------------------------------------------------------------------
// 1) integer degrees from edge list
// ---------------------------------------------------------------------------
__global__ __launch_bounds__(256) void degree_kernel(
    const int* __restrict__ src, const int* __restrict__ dst,
    int* __restrict__ deg_out, int* __restrict__ deg_in) {
  const int e = blockIdx.x * 256 + threadIdx.x;
  if (e < N_EDGES) {
    atomicAdd(&deg_out[src[e]], 1);
    atomicAdd(&deg_in[dst[e]], 1);
  }
}

// ---------------------------------------------------------------------------
// 2) multi-block exclusive scan of deg_in -> row_ptr[50001] + cursor
//    scan1: per-block sums; scan2: scan the 196 partials (in-place, excl);
//    scan3: per-block local scan + block offset.
// ---------------------------------------------------------------------------
__global__ __launch_bounds__(256) void scan1_kernel(
    const int* __restrict__ deg_in, int* __restrict__ partials) {
  __shared__ int red[256];
  const int i = blockIdx.x * 256 + threadIdx.x;
  red[threadIdx.x] = (i < N_NODES) ? deg_in[i] : 0;
  __syncthreads();
#pragma unroll
  for (int off = 128; off > 0; off >>= 1) {
    if (threadIdx.x < off) red[threadIdx.x] += red[threadIdx.x + off];
    __syncthreads();
  }
  if (threadIdx.x == 0) partials[blockIdx.x] = red[0];
}

__global__ __launch_bounds__(256) void scan2_kernel(int* __restrict__ partials) {
  __shared__ int s[256];
  const int tid = threadIdx.x;
  s[tid] = (tid < SCAN_BLOCKS) ? partials[tid] : 0;
  __syncthreads();
#pragma unroll
  for (int off = 1; off < 256; off <<= 1) {
    const int v = s[tid];
    const int add = (tid >= off) ? s[tid - off] : 0;
    __syncthreads();
    s[tid] = v + add;
    __syncthreads();
  }
  if (tid < SCAN_BLOCKS) partials[tid] = (tid == 0) ? 0 : s[tid - 1];
}

__global__ __launch_bounds__(256) void scan3_kernel(
    const int* __restrict__ deg_in, const int* __restrict__ partials,
    int* __restrict__ row_ptr, int* __restrict__ cursor) {
  __shared__ int s[256];
  const int tid = threadIdx.x;
  const int i = blockIdx.x * 256 + tid;
  const int v = (i < N_NODES) ? deg_in[i] : 0;
  s[tid] = v;
  __syncthreads();
#pragma unroll
  for (int off = 1; off < 256; off <<= 1) {
    const int x = s[tid];
    const int add = (tid >= off) ? s[tid - off] : 0;
    __syncthreads();
    s[tid] = x + add;
    __syncthreads();
  }
  if (i < N_NODES) {
    const int excl = partials[blockIdx.x] + s[tid] - v;
    row_ptr[i] = excl;
    cursor[i] = excl;
    if (i == N_NODES - 1) row_ptr[N_NODES] = excl + v;
  }
}

// ---------------------------------------------------------------------------
// 3) counting-sort edges by dst
// ---------------------------------------------------------------------------
__global__ __launch_bounds__(256) void fill_kernel(
    const int* __restrict__ src, const int* __restrict__ dst,
    int* __restrict__ cursor, int* __restrict__ esrc) {
  const int e = blockIdx.x * 256 + threadIdx.x;
  if (e < N_EDGES) {
    const int pos = atomicAdd(&cursor[dst[e]], 1);
    esrc[pos] = src[e];
  }
}

// ---------------------------------------------------------------------------
// 4) pull-mode aggregate from bf16 feat, fp32 accumulate -> bf16 agg (ws)
// ---------------------------------------------------------------------------
__global__ __launch_bounds__(256) void gather_kernel(
    const uint16_t* __restrict__ featb, const int* __restrict__ deg_out,
    const int* __restrict__ row_ptr, const int* __restrict__ esrc,
    uint16_t* __restrict__ agg) {
  const int n = blockIdx.x * 4 + (threadIdx.x >> 6);
  const int lane = threadIdx.x & 63;
  if (n >= N_NODES) return;
  const int beg = row_ptr[n];
  const int fin = row_ptr[n + 1];
  float4 acc = make_float4(0.f, 0.f, 0.f, 0.f);
  for (int j = beg; j < fin; ++j) {
    const int s = esrc[j];
    const float sc = rsqrtf(fmaxf((float)deg_out[s], 1.0f));
    const ushort4 q = *(const ushort4*)(featb + (size_t)s * DDIM + lane * 4);
    acc.x += bf16_to_f32(q.x) * sc;
    acc.y += bf16_to_f32(q.y) * sc;
    acc.z += bf16_to_f32(q.z) * sc;
    acc.w += bf16_to_f32(q.w) * sc;
  }
  ushort4 p;
  p.x = bf16_rne(acc.x);
  p.y = bf16_rne(acc.y);
  p.z = bf16_rne(acc.z);
  p.w = bf16_rne(acc.w);
  *(ushort4*)(agg + (size_t)n * DDIM + lane * 4) = p;
}

// ---------------------------------------------------------------------------
// 5) out = dropout(relu((agg @ W) * rsqrt(max(deg_in,1)) + b))
//    MFMA bf16 16x16x32.  Block = 64 rows x 256 cols, 4 waves (wave: 64x64).
// ---------------------------------------------------------------------------
#define APAD 280  // shorts per As row (560 B, 16B-aligned, 2-way banks)
#define BPAD 40   // shorts per Bs row (80 B, 16B-aligned, 2-way banks)
__global__ __launch_bounds__(256) void gemm_mfma_kernel(
    const uint16_t* __restrict__ agg, const uint16_t* __restrict__ Wt,
    const float* __restrict__ bias, const int* __restrict__ deg_in,
    float* __restrict__ out) {
  __shared__ short As[64 * APAD];
  __shared__ short Bs[256 * BPAD];
  __shared__ float sdeg[64];
  __shared__ float sbias[256];

  const int tid = threadIdx.x;
  const int r0 = blockIdx.x * 64;
  const int lane = tid & 63;
  const int seg = lane >> 4;  // k-segment 0..3
  const int l15 = lane & 15;
  const int wc = tid >> 6;  // wave -> col panel (64 cols each)

  sbias[tid] = bias[tid];
  if (tid < 64) {
    const int r = r0 + tid;
    sdeg[tid] = (r < N_NODES) ? rsqrtf(fmaxf((float)deg_in[r], 1.0f)) : 0.0f;
  }

  // stage A panel: 64 rows x 256 k bf16 (2048 x 16B chunks, coalesced)
  {
    const uint16_t* ap = agg + (size_t)r0 * DDIM;
#pragma unroll
    for (int it = 0; it < 8; ++it) {
      const int c = tid + 256 * it;
      const int row = c >> 5;        // 32 chunks per row
      const int k8 = (c & 31) << 3;  // 0,8,...,248
      int4 v = make_int4(0, 0, 0, 0);
      if (r0 + row < N_NODES) v = *(const int4*)(ap + (size_t)row * DDIM + k8);
      *(int4*)&As[row * APAD + k8] = v;
    }
  }

  f32x4 acc[4][4] = {};

  for (int kk = 0; kk < 256; kk += 32) {
    __syncthreads();  // A staged (first iter) / prev-iter Bs readers done
    // stage Bs: 256 n x 32 k bf16 from Wt (L2-resident)
#pragma unroll
    for (int it = 0; it < 4; ++it) {
      const int c = tid + 256 * it;  // 0..1023
      const int n = c >> 2;
      const int k8 = (c & 3) << 3;
      *(int4*)&Bs[n * BPAD + k8] = *(const int4*)(Wt + (size_t)n * DDIM + kk + k8);
    }
    __syncthreads();

    bf16x8 a[4], b[4];
#pragma unroll
    for (int m = 0; m < 4; ++m)
      a[m] = *(const bf16x8*)&As[(m * 16 + l15) * APAD + kk + seg * 8];
#pragma unroll
    for (int n = 0; n < 4; ++n)
      b[n] = *(const bf16x8*)&Bs[(wc * 64 + n * 16 + l15) * BPAD + seg * 8];
#pragma unroll
    for (int m = 0; m < 4; ++m)
#pragma unroll
      for (int n = 0; n < 4; ++n)
        acc[m][n] = __builtin_amdgcn_mfma_f32_16x16x32_bf16(a[m], b[n], acc[m][n], 0, 0, 0);
  }

  // epilogue: C/D layout col = lane&15, row = seg*4 + reg
#pragma unroll
  for (int m = 0; m < 4; ++m) {
#pragma unroll
    for (int r = 0; r < 4; ++r) {
      const int lrow = m * 16 + seg * 4 + r;
      const int row = r0 + lrow;
      if (row >= N_NODES) continue;
      const float s = sdeg[lrow];
#pragma unroll
      for (int n = 0; n < 4; ++n) {
        const int col = wc * 64 + n * 16 + l15;
        float v = acc[m][n][r] * s + sbias[col];
        v = fmaxf(v, 0.0f);
        const uint32_t flat = (uint32_t)row * 256u + (uint32_t)col;
        const uint32_t bits = threefry_draw_0_42(0u, flat);
        const float u = __uint_as_float((bits >> 9) | 0x3F800000u) - 1.0f;
        out[(size_t)row * DDIM + col] = (u < 0.9f) ? (v / 0.9f) : 0.0f;
      }
    }
  }
}

// ---------------------------------------------------------------------------
// ws layout (unchanged from round 7, proven <= ws_size):
//   ints:   deg_out [0,50000) | deg_in [50000,100000) | row_ptr [100000,150001)
//           cursor [150008,200008) | esrc [200008,600008)
//   bytes:  Wt bf16  @ 2400064  (131072 B)
//           agg bf16 @ 2531136  (25.6 MB)   total ~28.1 MB
// d_out scratch reuse (all before gemm overwrites d_out, stream-serialized):
//   featb bf16 @ d_out+0        (25.6 MB)
//   partials   @ d_out+40000000 (784 B)
// ---------------------------------------------------------------------------
extern "C" void kernel_launch(void* const* d_in, const int* in_sizes, int n_in,
                              void* d_out, int out_size, void* d_ws, size_t ws_size,
                              hipStream_t stream) {
  const float* feat = (const float*)d_in[0];
  const float* W = (const float*)d_in[1];
  const float* bias = (const float*)d_in[2];
  const int* src = (const int*)d_in[3];
  const int* dst = (const int*)d_in[4];
  float* out = (float*)d_out;

  int* iws = (int*)d_ws;
  int* deg_out = iws;
  int* deg_in = iws + 50000;
  int* row_ptr = iws + 100000;
  int* cursor = iws + 150008;
  int* esrc = iws + 200008;
  uint16_t* Wt = (uint16_t*)((char*)d_ws + 2400064);
  uint16_t* agg = (uint16_t*)((char*)d_ws + 2531136);
  uint16_t* featb = (uint16_t*)d_out;
  int* partials = (int*)((char*)d_out + 40000000);

  hipMemsetAsync(d_ws, 0, 100000 * sizeof(int), stream);  // degrees only

  wconv_kernel<<<64, 256, 0, stream>>>(W, Wt);
  fconv_kernel<<<6250, 256, 0, stream>>>(feat, featb);
  degree_kernel<<<(N_EDGES + 255) / 256, 256, 0, stream>>>(src, dst, deg_out, deg_in);
  scan1_kernel<<<SCAN_BLOCKS, 256, 0, stream>>>(deg_in, partials);
  scan2_kernel<<<1, 256, 0, stream>>>(partials);
  scan3_kernel<<<SCAN_BLOCKS, 256, 0, stream>>>(deg_in, partials, row_ptr, cursor);
  fill_kernel<<<(N_EDGES + 255) / 256, 256, 0, stream>>>(src, dst, cursor, esrc);
  gather_kernel<<<(N_NODES + 3) / 4, 256, 0, stream>>>(featb, deg_out, row_ptr, esrc, agg);
  gemm_mfma_kernel<<<(N_NODES + 63) / 64, 256, 0, stream>>>(agg, Wt, bias, deg_in, out);
}